// Round 12
// baseline (166.476 us; speedup 1.0000x reference)
//
#include <hip/hip_runtime.h>
#include <stdint.h>

// out[n,o] = sum_{d,i} q[n,d] x[n,i] W1[d,i,o] + (q @ b1)[n,o]
// GEMM M=4096 N=256 K=16384 (k = d*256 + i), fp16 MFMA 32x32x16, fp32 accum.
//
// ROUND 12 = ROUND 11 resubmitted verbatim (container infra failure, kernel
// never ran). Theory unchanged:
// R8 structure (best main, 46 us) at 3 waves/SIMD without a register cliff.
// R10's launch_bounds(512,4)=128 forced a spill (VGPR=64 arch + 64 AGPR,
// FETCH/WRITE = spill traffic). Now: 256-thr blocks (4 waves), grid 1024 =
// 32 mb x 8 nc x 4 ksi (i-quarters). Block = 128 rows x 32 cols; wave owns
// 16 d's x 4 ics = 64 chunks, 1 W-load : 4 MFMA. launch_bounds(256,3) = 170
// regs vs ~148 used -> 3 blocks/CU (12 waves/CU, 3/SIMD, 1.5x R8). W ring
// depth 4 runs across icc boundaries; x double-buffered, issued one icc
// (~2000 cy) ahead and BEFORE subsequent W issues so in-order vmcnt
// retirement never drains the ring. d-rotation rot=(mb+4ksi)&15 staggers
// same-slice readers (q loaded rotated, hot loop static). Epilogue:
// two-phase LDS d-reduce (36.9 KB) -> 4 fp32 stripes + reduce4. Bias q@b1
// folded into wave 3 of ksi==0 blocks.

typedef _Float16 f16;
typedef f16 f16x8 __attribute__((ext_vector_type(8)));
typedef float f32x16 __attribute__((ext_vector_type(16)));

#define QDIM 64

// one fp32-float8 -> f16x8
#define XFRAG(DST, PTR)                                      \
  do {                                                       \
    float4 a_ = *(const float4*)(PTR);                       \
    float4 b_ = *(const float4*)((PTR) + 4);                 \
    f16x8 h_;                                                \
    h_[0] = (f16)a_.x; h_[1] = (f16)a_.y; h_[2] = (f16)a_.z; \
    h_[3] = (f16)a_.w; h_[4] = (f16)b_.x; h_[5] = (f16)b_.y; \
    h_[6] = (f16)b_.z; h_[7] = (f16)b_.w;                    \
    DST = h_;                                                \
  } while (0)

// ---------------- prep (unchanged from R9/R10 — verified) ----------------
// Wt layout (8 MB):  byte = ((ncg*64 + d)*16 + ic)*1024 + hf*512 + c*16 + j*2
//   <- W1[d][ic*16 + hf*8 + j][ncg*32 + c]   (B-frag lane-linear, 1KB chunks)
// Xt layout (2 MB):  byte = ((t64*16 + ic)*2 + hf)*1024 + row*16 + j*2
//   <- x[t64*64 + row][ic*16 + hf*8 + j]     (A-frag lane-linear, 64-row tiles)
// Bt layout (32 KB): byte = ((ncg*4 + kc)*2 + hf)*512 + c*16 + j*2
//   <- b1[kc*16 + hf*8 + j][ncg*32 + c]
__global__ __launch_bounds__(256) void prep(const float* __restrict__ W,
                                            const float* __restrict__ B1,
                                            const float* __restrict__ X,
                                            f16* __restrict__ Wt,
                                            f16* __restrict__ Xt,
                                            f16* __restrict__ Bt) {
  const int b = blockIdx.x, t = threadIdx.x;
  if (b < 512) {
    const int d = b >> 3, grp = b & 7;
#pragma unroll
    for (int r = 0; r < 4; ++r) {
      const int u = (r << 8) + t;
      const int ibq = u >> 8;
      const int o = u & 255;
      const int ib = (grp << 2) + ibq;  // i = ib*8 + j
      f16x8 h;
#pragma unroll
      for (int j = 0; j < 8; ++j)
        h[j] = (f16)W[((size_t)d * 256 + (ib << 3) + j) * 256 + o];
      const int ncg = o >> 5, c = o & 31, ic = ib >> 1, hb = ib & 1;
      *(f16x8*)((char*)Wt + ((((size_t)ncg * 64 + d) * 16 + ic) << 10) +
                (hb << 9) + (c << 4)) = h;
    }
  } else if (b < 576) {
    const int mb = b - 512;  // 64-row tiles
#pragma unroll
    for (int rep = 0; rep < 8; ++rep) {
      const int u = (rep << 8) + t;
      const int row = u & 63, ish = u >> 6;  // i = ish*8 + j
      const float* src = X + ((size_t)((mb << 6) + row)) * 256 + (ish << 3);
      f16x8 h;
      XFRAG(h, src);
      *(f16x8*)((char*)Xt + ((((size_t)mb * 16 + (ish >> 1)) * 2 + (ish & 1)) << 10) +
                (row << 4)) = h;
    }
  } else {
#pragma unroll
    for (int kb = 0; kb < 8; ++kb) {  // k = kb*8 + j
      const float* src = B1 + ((size_t)kb << 3) * 256 + t;
      f16x8 h;
#pragma unroll
      for (int j = 0; j < 8; ++j) h[j] = (f16)src[(size_t)j << 8];
      *(f16x8*)((char*)Bt + (((size_t)(t >> 5) * 4 + (kb >> 1)) << 10) +
                ((kb & 1) << 9) + ((t & 31) << 4)) = h;
    }
  }
}

// ---- main: 1024 blocks = 32 mb (128 rows) x 8 nc (32 cols) x 4 ksi (4 ics) --
__global__ __launch_bounds__(256, 3) void mlp_main(const float* __restrict__ Q,
                                                   const f16* __restrict__ Wt,
                                                   const f16* __restrict__ Xt,
                                                   const f16* __restrict__ Bt,
                                                   float* __restrict__ P) {
  __shared__ __align__(16) float red[2][128][36];  // 36.9 KB

  const int bid = blockIdx.x;
  const int nc = bid & 7;          // XCD-affine column tile (32 cols)
  const int ksi = (bid >> 3) & 3;  // i-quarter (4 ics)
  const int mb = bid >> 5;         // 0..31, 128-row tile
  const int t = threadIdx.x;
  const int w = t >> 6;            // 0..3, d-range [w*16, w*16+16)
  const int l = t & 63;
  const int l31 = l & 31;
  const int hf = l >> 5;
  const int rot = (mb + (ksi << 2)) & 15;  // d-walk stagger

  // W chunk (ddAbs, icc): nc<<20 + w<<18 + ddAbs<<14 + ksi<<12 + icc<<10
  const char* wB = (const char*)Wt + ((size_t)nc << 20) + (w << 18) +
                   (ksi << 12) + (l << 4);
#define WADDR(S) \
  (wB + (((((S) & 15) + rot) & 15) << 14) + (((S) >> 4) << 10))

  // x frag (mt, icAbs = ksi*4 + icc): xB + (mt>>1)<<15 + icAbs<<11 + (mt&1)<<9
  const char* xB = (const char*)Xt + ((size_t)mb << 16) + (hf << 10) + (l31 << 4);
#define LOADXF(D, ICC)                                                       \
  do {                                                                      \
    _Pragma("unroll")                                                       \
    for (int mt_ = 0; mt_ < 4; ++mt_)                                       \
      D[mt_] = *(const f16x8*)(xB + ((mt_ >> 1) << 15) +                    \
                               ((size_t)((ksi << 2) + (ICC)) << 11) +       \
                               ((mt_ & 1) << 9));                           \
  } while (0)

  // q scalars, rotated: qv[mt*2 + (dt>>3)][dt&7] = q[row_mt][w*16 + (dt+rot)&15]
  f16x8 qv[8];
#pragma unroll
  for (int mt = 0; mt < 4; ++mt) {
    const float* qp = Q + ((size_t)((mb << 7) + (mt << 5) + l31)) * QDIM + (w << 4);
#pragma unroll
    for (int dt = 0; dt < 16; ++dt)
      qv[(mt << 1) + (dt >> 3)][dt & 7] = (f16)qp[(dt + rot) & 15];
  }

  f32x16 acc0, acc1, acc2, acc3;
#pragma unroll
  for (int r = 0; r < 16; ++r) { acc0[r] = 0.f; acc1[r] = 0.f;
                                 acc2[r] = 0.f; acc3[r] = 0.f; }

  f16x8 Wr0, Wr1, Wr2, Wr3, xfA[4], xfB[4];

  // prologue: xfA(icc=0) first, then W ring s=0..3 (xf waits won't drain ring)
  LOADXF(xfA, 0);
  Wr0 = *(const f16x8*)WADDR(0);
  Wr1 = *(const f16x8*)WADDR(1);
  Wr2 = *(const f16x8*)WADDR(2);
  Wr3 = *(const f16x8*)WADDR(3);

// one chunk: consume WR (chunk S), prefetch chunk S+4, 4 MFMA
#define STEP(S, WR, XF)                                                      \
  do {                                                                      \
    f16x8 wf_ = WR;                                                         \
    if ((S) < 60) WR = *(const f16x8*)WADDR((S) + 4);                       \
    acc0 = __builtin_amdgcn_mfma_f32_32x32x16_f16(                          \
        XF[0] * qv[0 + (((S) >> 3) & 1)][(S) & 7], wf_, acc0, 0, 0, 0);     \
    acc1 = __builtin_amdgcn_mfma_f32_32x32x16_f16(                          \
        XF[1] * qv[2 + (((S) >> 3) & 1)][(S) & 7], wf_, acc1, 0, 0, 0);     \
    acc2 = __builtin_amdgcn_mfma_f32_32x32x16_f16(                          \
        XF[2] * qv[4 + (((S) >> 3) & 1)][(S) & 7], wf_, acc2, 0, 0, 0);     \
    acc3 = __builtin_amdgcn_mfma_f32_32x32x16_f16(                          \
        XF[3] * qv[6 + (((S) >> 3) & 1)][(S) & 7], wf_, acc3, 0, 0, 0);     \
  } while (0)

#define STEP16(B, XF)                                                        \
  STEP((B) + 0, Wr0, XF);  STEP((B) + 1, Wr1, XF);                           \
  STEP((B) + 2, Wr2, XF);  STEP((B) + 3, Wr3, XF);                           \
  STEP((B) + 4, Wr0, XF);  STEP((B) + 5, Wr1, XF);                           \
  STEP((B) + 6, Wr2, XF);  STEP((B) + 7, Wr3, XF);                           \
  STEP((B) + 8, Wr0, XF);  STEP((B) + 9, Wr1, XF);                           \
  STEP((B) + 10, Wr2, XF); STEP((B) + 11, Wr3, XF);                          \
  STEP((B) + 12, Wr0, XF); STEP((B) + 13, Wr1, XF);                          \
  STEP((B) + 14, Wr2, XF); STEP((B) + 15, Wr3, XF)

  // 64 chunks = 4 icc x 16 dd; x prefetched one icc ahead, before W issues
  LOADXF(xfB, 1);
  STEP16(0, xfA);
  LOADXF(xfA, 2);
  STEP16(16, xfB);
  LOADXF(xfB, 3);
  STEP16(32, xfA);
  STEP16(48, xfB);

  // bias (ksi==0, wave 3): 4 chunks over QDIM, A = q-frag, B = Bt
  if (ksi == 0 && w == 3) {
#pragma unroll
    for (int kc = 0; kc < 4; ++kc) {
      f16x8 bf = *(const f16x8*)((const char*)Bt +
          (((size_t)nc * 4 + kc) << 10) + (hf << 9) + (l31 << 4));
      f16x8 q0, q1, q2, q3;
      XFRAG(q0, Q + ((size_t)((mb << 7) + l31)) * QDIM + (kc << 4) + (hf << 3));
      XFRAG(q1, Q + ((size_t)((mb << 7) + 32 + l31)) * QDIM + (kc << 4) + (hf << 3));
      XFRAG(q2, Q + ((size_t)((mb << 7) + 64 + l31)) * QDIM + (kc << 4) + (hf << 3));
      XFRAG(q3, Q + ((size_t)((mb << 7) + 96 + l31)) * QDIM + (kc << 4) + (hf << 3));
      acc0 = __builtin_amdgcn_mfma_f32_32x32x16_f16(q0, bf, acc0, 0, 0, 0);
      acc1 = __builtin_amdgcn_mfma_f32_32x32x16_f16(q1, bf, acc1, 0, 0, 0);
      acc2 = __builtin_amdgcn_mfma_f32_32x32x16_f16(q2, bf, acc2, 0, 0, 0);
      acc3 = __builtin_amdgcn_mfma_f32_32x32x16_f16(q3, bf, acc3, 0, 0, 0);
    }
  }

  // ---- two-phase 4-way d-reduction in LDS ----
  // C/D (32x32): col = lane&31, row = (reg&3) + 8*(reg>>2) + 4*(lane>>5)
  if (w < 2) {
#pragma unroll
    for (int r = 0; r < 16; ++r) {
      const int rr = (r & 3) + ((r >> 2) << 3) + (hf << 2);
      red[w][rr][l31] = acc0[r];
      red[w][32 + rr][l31] = acc1[r];
      red[w][64 + rr][l31] = acc2[r];
      red[w][96 + rr][l31] = acc3[r];
    }
  }
  __syncthreads();
  if (w >= 2) {
#pragma unroll
    for (int r = 0; r < 16; ++r) {
      const int rr = (r & 3) + ((r >> 2) << 3) + (hf << 2);
      red[w - 2][rr][l31] += acc0[r];
      red[w - 2][32 + rr][l31] += acc1[r];
      red[w - 2][64 + rr][l31] += acc2[r];
      red[w - 2][96 + rr][l31] += acc3[r];
    }
  }
  __syncthreads();

  // final: 256 threads x 16 cols; sum the 2 regions; store to stripe ksi
  const int row = t >> 1;
  const int c0 = (t & 1) << 4;
  float* op = P + ((size_t)ksi << 20) +
              ((size_t)((mb << 7) + row)) * 256 + (nc << 5) + c0;
#pragma unroll
  for (int g = 0; g < 4; ++g) {
    float4 v0 = *(const float4*)(&red[0][row][c0 + (g << 2)]);
    float4 v1 = *(const float4*)(&red[1][row][c0 + (g << 2)]);
    v0.x += v1.x; v0.y += v1.y; v0.z += v1.z; v0.w += v1.w;
    *(float4*)(op + (g << 2)) = v0;
  }
}

// out = P[0]+P[1]+P[2]+P[3]. 1024 blocks x 256 threads x float4.
__global__ __launch_bounds__(256) void reduce4(const float* __restrict__ P,
                                               float* __restrict__ out) {
  const size_t i = (((size_t)blockIdx.x << 8) + threadIdx.x) << 2;
  float4 s = *(const float4*)(P + i);
#pragma unroll
  for (int g = 1; g < 4; ++g) {
    float4 v = *(const float4*)(P + ((size_t)g << 20) + i);
    s.x += v.x; s.y += v.y; s.z += v.z; s.w += v.w;
  }
  *(float4*)(out + i) = s;
}

extern "C" void kernel_launch(void* const* d_in, const int* in_sizes, int n_in,
                              void* d_out, int out_size, void* d_ws, size_t ws_size,
                              hipStream_t stream) {
  (void)in_sizes; (void)n_in; (void)out_size; (void)ws_size;
  const float* x  = (const float*)d_in[0];   // [4096,256]
  const float* q  = (const float*)d_in[1];   // [4096,64]
  const float* W1 = (const float*)d_in[2];   // [64,256,256]
  const float* b1 = (const float*)d_in[3];   // [64,256]
  float* out = (float*)d_out;                // [4096,256] fp32

  // ws: Wt 8 MB | Bt 32 KB | Xt 2 MB | P 4 x 4 MB  (~26 MB)
  f16* Wt = (f16*)d_ws;
  f16* Bt = (f16*)((char*)d_ws + ((size_t)8 << 20));
  f16* Xt = (f16*)((char*)d_ws + ((size_t)8 << 20) + 32768);
  float* P = (float*)((char*)d_ws + ((size_t)8 << 20) + 32768 + ((size_t)2 << 20));

  prep<<<577, 256, 0, stream>>>(W1, b1, x, Wt, Xt, Bt);
  mlp_main<<<1024, 256, 0, stream>>>(q, Wt, Xt, Bt, P);
  reduce4<<<1024, 256, 0, stream>>>(P, out);
}

// Round 13
// 116.989 us; speedup vs baseline: 1.4230x; 1.4230x over previous
//
#include <hip/hip_runtime.h>
#include <stdint.h>

// out[n,o] = sum_{d,i} q[n,d] x[n,i] W1[d,i,o] + (q @ b1)[n,o]
// GEMM M=4096 N=256 K=16384 (k = d*256 + i), fp16 MFMA 32x32x16, fp32 accum.
//
// ROUND 13: bank a safe gain. Main = round-8 kernel VERBATIM (best measured:
// 46.3 us, VGPR 128+64 no spill). R12 proved the (256,3) unified budget is
// ~148 regs -> 3 waves/SIMD unreachable with acc=64 AGPR + ring state; stop
// gambling on main. Attack prep instead (~27 us vs 12.5 us roofline):
// prep-W = one wave per 1KB chunk; lane (hf,c) reads 8 strided fp32 (two
// 128B segments per load inst), wave's f16x8 store writes a perfectly
// contiguous 1KB. Grid 2113 light blocks (load balance, no tail).
// Structure of main: full-K blocks, tile 64x32, grid 512 = 64 mb x 8 nc;
// 4 waves split d (16 each); depth-16 W register ring; ic-stagger; LDS
// cross-wave d-reduction; direct fp32 stores. 2 dispatches, no memset.

typedef _Float16 f16;
typedef f16 f16x8 __attribute__((ext_vector_type(8)));
typedef float f32x16 __attribute__((ext_vector_type(16)));

#define QDIM 64

// one fp32-float8 -> f16x8
#define XFRAG(DST, PTR)                                      \
  do {                                                       \
    float4 a_ = *(const float4*)(PTR);                       \
    float4 b_ = *(const float4*)((PTR) + 4);                 \
    f16x8 h_;                                                \
    h_[0] = (f16)a_.x; h_[1] = (f16)a_.y; h_[2] = (f16)a_.z; \
    h_[3] = (f16)a_.w; h_[4] = (f16)b_.x; h_[5] = (f16)b_.y; \
    h_[6] = (f16)b_.z; h_[7] = (f16)b_.w;                    \
    DST = h_;                                                \
  } while (0)

// ---------------- prep ----------------
// Wt layout (8 MB):  byte = ((ncg*64 + d)*16 + ic)*1024 + hf*512 + c*16 + j*2
//   <- W1[d][ic*16 + hf*8 + j][ncg*32 + c]   (B-frag lane-linear, 1KB chunks)
// Xt layout (2 MB):  byte = ((t64*16 + ic)*2 + hf)*1024 + row*16 + j*2
//   <- x[t64*64 + row][ic*16 + hf*8 + j]     (A-frag lane-linear, 64-row tiles)
// Bt layout (32 KB): byte = ((ncg*4 + kc)*2 + hf)*512 + c*16 + j*2
//   <- b1[kc*16 + hf*8 + j][ncg*32 + c]
// grid 2113: [0,2048) W (1 chunk/wave) | [2048,2112) Xt | 2112 Bt
__global__ __launch_bounds__(256) void prep(const float* __restrict__ W,
                                            const float* __restrict__ B1,
                                            const float* __restrict__ X,
                                            f16* __restrict__ Wt,
                                            f16* __restrict__ Xt,
                                            f16* __restrict__ Bt) {
  const int b = blockIdx.x, t = threadIdx.x;
  if (b < 2048) {
    const int w = t >> 6, l = t & 63, hf = l >> 5, c = l & 31;
    const int g = (b << 2) + w;   // chunk id 0..8191 = (ncg*64 + d)*16 + ic
    const int ic = g & 15;
    const int d = (g >> 4) & 63;
    const int ncg = g >> 10;
    const float* src = W + ((size_t)(d * 256 + (ic << 4) + (hf << 3)) << 8) +
                       (ncg << 5) + c;
    f16x8 h;
#pragma unroll
    for (int j = 0; j < 8; ++j) h[j] = (f16)src[(size_t)j << 8];
    *(f16x8*)((char*)Wt + ((size_t)g << 10) + (hf << 9) + (c << 4)) = h;
  } else if (b < 2112) {
    const int mb = b - 2048;  // 64-row tiles
#pragma unroll
    for (int rep = 0; rep < 8; ++rep) {
      const int u = (rep << 8) + t;          // 0..2047
      const int row = u & 63, ish = u >> 6;  // i = ish*8 + j
      const float* src = X + ((size_t)((mb << 6) + row)) * 256 + (ish << 3);
      f16x8 h;
      XFRAG(h, src);
      *(f16x8*)((char*)Xt + ((((size_t)mb * 16 + (ish >> 1)) * 2 + (ish & 1)) << 10) +
                (row << 4)) = h;
    }
  } else {
#pragma unroll
    for (int kb = 0; kb < 8; ++kb) {  // k = kb*8 + j
      const float* src = B1 + ((size_t)kb << 3) * 256 + t;
      f16x8 h;
#pragma unroll
      for (int j = 0; j < 8; ++j) h[j] = (f16)src[(size_t)j << 8];
      *(f16x8*)((char*)Bt + (((size_t)(t >> 5) * 4 + (kb >> 1)) << 10) +
                ((kb & 1) << 9) + ((t & 31) << 4)) = h;
    }
  }
}

// load the 4 x frags (mt=0..3) for one ic
#define LOADX4(D, IC)                                                        \
  do {                                                                       \
    _Pragma("unroll")                                                        \
    for (int mt_ = 0; mt_ < 4; ++mt_)                                        \
      D[mt_] = *(const f16x8*)(xB + ((mt_ >> 1) << 15) + ((mt_ & 1) << 9) +  \
                               ((size_t)(IC) << 11));                        \
  } while (0)

// consume the 8-d ring for one ic (frags already in Wr), prefetch ic ICN.
#define DPASS(XF, ICN)                                                       \
  do {                                                                       \
    _Pragma("unroll")                                                        \
    for (int dd_ = 0; dd_ < 8; ++dd_) {                                      \
      f16x8 wf_ = Wr[dd_];                                                   \
      Wr[dd_] = *(const f16x8*)(wl + (((size_t)((dd_ << 4) + (ICN))) << 10));\
      _Pragma("unroll")                                                      \
      for (int mt_ = 0; mt_ < 4; ++mt_) {                                    \
        f16x8 a_ = XF[mt_] * qr[mt_][dd_];                                   \
        acc[mt_] = __builtin_amdgcn_mfma_f32_32x32x16_f16(a_, wf_,           \
                                                          acc[mt_], 0, 0, 0);\
      }                                                                      \
    }                                                                        \
  } while (0)

// ---- main: 256 blocks = 32 mb-tiles (128 rows) x 8 col-tiles (32 cols) ----
// 512 threads = 8 waves; wave w owns d-range [w*8, w*8+8), computes the full
// 128x32 tile for those d's. Two-phase LDS d-reduction at the end.
__global__ __launch_bounds__(512, 2) void mlp_main(const float* __restrict__ Q,
                                                   const f16* __restrict__ Wt,
                                                   const f16* __restrict__ Xt,
                                                   const f16* __restrict__ Bt,
                                                   float* __restrict__ out) {
  __shared__ __align__(16) float red[4][128][36];  // 73.7 KB, epilogue only

  const int bid = blockIdx.x;
  const int nc = bid & 7;   // XCD-affine column tile
  const int mb = bid >> 3;  // 0..31, 128-row tile
  const int t = threadIdx.x;
  const int w = t >> 6;     // 0..7, d-range [w*8, w*8+8)
  const int l = t & 63;
  const int l31 = l & 31;
  const int hf = l >> 5;

  // per-lane W base: chunk (dd, ic) at + (dd*16 + ic)*1024
  const char* wl = (const char*)Wt + (((size_t)(nc * 64 + (w << 3))) << 14) +
                   (hf << 9) + (l31 << 4);
  // x frag (mt, ic): tile64 = mb*2 + (mt>>1), row = (mt&1)*32 + l31
  const char* xB = (const char*)Xt + ((size_t)(mb << 1) << 15) + (hf << 10) +
                   ((size_t)l31 << 4);

  // q scalars: q[mb*128 + mt*32 + l31][w*8 + dd]  (float8 per mt)
  f16 qr[4][8];
#pragma unroll
  for (int mt = 0; mt < 4; ++mt) {
    const float* qp = Q + (size_t)((mb << 7) + (mt << 5) + l31) * QDIM + (w << 3);
    float4 a = *(const float4*)qp;
    float4 c = *(const float4*)(qp + 4);
    qr[mt][0] = (f16)a.x; qr[mt][1] = (f16)a.y;
    qr[mt][2] = (f16)a.z; qr[mt][3] = (f16)a.w;
    qr[mt][4] = (f16)c.x; qr[mt][5] = (f16)c.y;
    qr[mt][6] = (f16)c.z; qr[mt][7] = (f16)c.w;
  }

  f32x16 acc[4];
#pragma unroll
  for (int mt = 0; mt < 4; ++mt)
#pragma unroll
    for (int r = 0; r < 16; ++r) acc[mt][r] = 0.f;

  f16x8 Wr[8], xfA[4], xfB[4];

  // ic-stagger: same-XCD blocks start at 8 phases
  const int icoff = (mb & 7) << 1;  // even

  // prologue: ring for ic=icoff, x frags for icoff
#pragma unroll
  for (int dd = 0; dd < 8; ++dd)
    Wr[dd] = *(const f16x8*)(wl + (((size_t)((dd << 4) + icoff)) << 10));
  LOADX4(xfA, icoff);

  for (int s2 = 0; s2 < 8; ++s2) {
    const int icO = (icoff + (s2 << 1) + 1) & 15;  // odd position
    const int icE = (icoff + (s2 << 1) + 2) & 15;  // next even position
    LOADX4(xfB, icO);
    DPASS(xfA, icO);   // consume even ic, prefetch odd into ring
    LOADX4(xfA, icE);  // s2==7: dummy reload (unused)
    DPASS(xfB, icE);   // consume odd, prefetch next even (s2==7: dead wrap)
  }

  // bias (wave 7 only): 4 chunks over QDIM, A = q-frag, B = Bt
  if (w == 7) {
#pragma unroll
    for (int kc = 0; kc < 4; ++kc) {
      f16x8 bf = *(const f16x8*)((const char*)Bt +
          (((size_t)nc * 4 + kc) << 10) + (hf << 9) + (l31 << 4));
#pragma unroll
      for (int mt = 0; mt < 4; ++mt) {
        f16x8 qf;
        XFRAG(qf, Q + (size_t)((mb << 7) + (mt << 5) + l31) * QDIM +
                  (kc << 4) + (hf << 3));
        acc[mt] = __builtin_amdgcn_mfma_f32_32x32x16_f16(qf, bf, acc[mt], 0, 0, 0);
      }
    }
  }

  // ---- two-phase 8-way d-reduction in LDS ----
  // C/D (32x32): col = lane&31, row = (reg&3) + 8*(reg>>2) + 4*(lane>>5)
  if (w < 4) {
#pragma unroll
    for (int mt = 0; mt < 4; ++mt)
#pragma unroll
      for (int r = 0; r < 16; ++r) {
        const int row = (mt << 5) + (r & 3) + ((r >> 2) << 3) + (hf << 2);
        red[w][row][l31] = acc[mt][r];
      }
  }
  __syncthreads();
  if (w >= 4) {
#pragma unroll
    for (int mt = 0; mt < 4; ++mt)
#pragma unroll
      for (int r = 0; r < 16; ++r) {
        const int row = (mt << 5) + (r & 3) + ((r >> 2) << 3) + (hf << 2);
        red[w - 4][row][l31] += acc[mt][r];
      }
  }
  __syncthreads();

  // final: 512 threads x 8 outputs; sum the 4 regions
  const int r = t >> 2;         // 0..127
  const int c0 = (t & 3) << 3;  // 0,8,16,24
  float s[8];
#pragma unroll
  for (int j = 0; j < 8; ++j) s[j] = 0.f;
#pragma unroll
  for (int j = 0; j < 4; ++j) {
    const float* rp = &red[j][r][c0];
    float4 v0 = *(const float4*)rp;
    float4 v1 = *(const float4*)(rp + 4);
    s[0] += v0.x; s[1] += v0.y; s[2] += v0.z; s[3] += v0.w;
    s[4] += v1.x; s[5] += v1.y; s[6] += v1.z; s[7] += v1.w;
  }
  float4 o0 = {s[0], s[1], s[2], s[3]};
  float4 o1 = {s[4], s[5], s[6], s[7]};
  float* op = out + ((size_t)((mb << 7) + r)) * 256 + (nc << 5) + c0;
  *(float4*)op = o0;
  *(float4*)(op + 4) = o1;
}

extern "C" void kernel_launch(void* const* d_in, const int* in_sizes, int n_in,
                              void* d_out, int out_size, void* d_ws, size_t ws_size,
                              hipStream_t stream) {
  (void)in_sizes; (void)n_in; (void)out_size; (void)ws_size;
  const float* x  = (const float*)d_in[0];   // [4096,256]
  const float* q  = (const float*)d_in[1];   // [4096,64]
  const float* W1 = (const float*)d_in[2];   // [64,256,256]
  const float* b1 = (const float*)d_in[3];   // [64,256]
  float* out = (float*)d_out;                // [4096,256] fp32

  // ws: Wt 8 MB | Bt 32 KB | Xt 2 MB  (~10.03 MB)
  f16* Wt = (f16*)d_ws;
  f16* Bt = (f16*)((char*)d_ws + ((size_t)8 << 20));
  f16* Xt = (f16*)((char*)d_ws + ((size_t)8 << 20) + 32768);

  prep<<<2113, 256, 0, stream>>>(W1, b1, x, Wt, Xt, Bt);
  mlp_main<<<256, 512, 0, stream>>>(q, Wt, Xt, Bt, out);
}